// Round 14
// baseline (329.023 us; speedup 1.0000x reference)
//
#include <hip/hip_runtime.h>
#include <math.h>
#include <float.h>

#define NNODES 50000
#define NEDGES 800000
// feature dims: in=hid=out=128, heads=4, head_dim=32

// ---- CSR binning params ----
#define KB    196                       // coarse bins (dst>>8), covers 50176 nodes
#define NPB   256                       // nodes per bin
#define CAPB  4608                      // per-bin capacity (mean 4081, +8 sigma)
#define EPB   4096                      // edges per pass-A block
#define NABLK ((NEDGES + EPB - 1) / EPB)   // 196
#define HSZ   (NNODES * 32)             // per-head slice size (halves)

typedef __attribute__((ext_vector_type(4))) _Float16 half4;
typedef __attribute__((ext_vector_type(8))) _Float16 half8;
typedef __attribute__((ext_vector_type(4))) float f32x4;

// ---------------- CSR build, two-pass LDS binning ----------------
__global__ __launch_bounds__(256) void bininit_kernel(int* __restrict__ bincur) {
    int t = threadIdx.x;
    if (t < KB) bincur[t] = t * CAPB;
}

__global__ __launch_bounds__(256) void binA_kernel(
    const int* __restrict__ src, const int* __restrict__ dst,
    int* __restrict__ bincur, unsigned* __restrict__ binned)
{
    __shared__ int lhist[KB];
    __shared__ int lstart[KB];
    __shared__ int lcur[KB];
    __shared__ int gbase[KB];
    __shared__ unsigned lbuf[EPB];
    __shared__ int wtot[4];

    int t = threadIdx.x;
    int e0 = blockIdx.x * EPB;
    int ecnt = NEDGES - e0; if (ecnt > EPB) ecnt = EPB;

    for (int b = t; b < KB; b += 256) lhist[b] = 0;
    __syncthreads();

    for (int idx = t; idx < ecnt; idx += 256)
        atomicAdd(&lhist[((unsigned)dst[e0 + idx]) >> 8], 1);
    __syncthreads();

    {
        int lane = t & 63, w = t >> 6;
        int v = (t < KB) ? lhist[t] : 0;
        int x = v;
#pragma unroll
        for (int off = 1; off < 64; off <<= 1) {
            int y = __shfl_up(x, off, 64);
            if (lane >= off) x += y;
        }
        if (lane == 63) wtot[w] = x;
        __syncthreads();
        int wpre = 0;
#pragma unroll
        for (int j = 0; j < 4; ++j) if (j < w) wpre += wtot[j];
        int ex = wpre + x - v;
        if (t < KB) { lstart[t] = ex; lcur[t] = ex; }
    }
    __syncthreads();

    if (t < KB) {
        int c = lhist[t];
        gbase[t] = c ? atomicAdd(&bincur[t], c) : 0;
    }
    __syncthreads();

    for (int idx = t; idx < ecnt; idx += 256) {
        unsigned d = (unsigned)dst[e0 + idx];
        unsigned s = (unsigned)src[e0 + idx];
        int pos = atomicAdd(&lcur[d >> 8], 1);
        lbuf[pos] = (d << 16) | s;
    }
    __syncthreads();

    for (int idx = t; idx < ecnt; idx += 256) {
        unsigned p = lbuf[idx];
        int b = p >> 24;
        binned[gbase[b] + (idx - lstart[b])] = p;
    }
}

__global__ __launch_bounds__(256) void binB_kernel(
    const unsigned* __restrict__ binned, const int* __restrict__ bincur,
    unsigned short* __restrict__ csr_src, int2* __restrict__ node_info)
{
    __shared__ int lhist[NPB];
    __shared__ int lcur[NPB];
    __shared__ int wtot[4];
    int k = blockIdx.x;
    int t = threadIdx.x;
    int base = k * CAPB;
    int cnt = bincur[k] - base;

    lhist[t] = 0;
    __syncthreads();

    for (int i = t; i < cnt; i += 256)
        atomicAdd(&lhist[(binned[base + i] >> 16) & 0xFF], 1);
    __syncthreads();

    int lane = t & 63, w = t >> 6;
    int v = lhist[t];
    int x = v;
#pragma unroll
    for (int off = 1; off < 64; off <<= 1) {
        int y = __shfl_up(x, off, 64);
        if (lane >= off) x += y;
    }
    if (lane == 63) wtot[w] = x;
    __syncthreads();
    int wpre = 0;
#pragma unroll
    for (int j = 0; j < 4; ++j) if (j < w) wpre += wtot[j];
    int ex = wpre + x - v;
    lcur[t] = ex;
    int node = k * NPB + t;
    if (node < NNODES) node_info[node] = make_int2(base + ex, v);
    __syncthreads();

    for (int i = t; i < cnt; i += 256) {
        unsigned p = binned[base + i];
        int ln = (p >> 16) & 0xFF;
        int pos = atomicAdd(&lcur[ln], 1);
        csr_src[base + pos] = (unsigned short)(p & 0xFFFFu);
    }
}

// ---------------- prep: W0/W1 -> fp16 transposed [col][k] -------
__global__ __launch_bounds__(256) void prepw_kernel(
    const float* __restrict__ W0, const float* __restrict__ W1,
    _Float16* __restrict__ W0t, _Float16* __restrict__ W1t)
{
    int idx = blockIdx.x * 256 + threadIdx.x;
    if (idx < 128 * 128) {
        int cc = idx >> 7, k = idx & 127;
        W0t[idx] = (_Float16)W0[k * 128 + cc];
        W1t[idx] = (_Float16)W1[k * 128 + cc];
    }
}

// ---------------- MFMA GEMM + alpha: h = A@W ; alpha_s/d = <h, a_*> -------
// A: fp32 row-major (layer 0, converted in staging) or fp16 HEAD-MAJOR
// [4][N][32] (layer 1). Wt fp16 [128 cols][128 k]. h output HEAD-MAJOR.
// Block = 256 thr = 4 waves; tile 64 x 128. Frag mapping verified (r12).
#define GP 136
template <bool F32IN>
__global__ __launch_bounds__(256) void gemm_mfma_kernel(
    const void* __restrict__ Ain, const _Float16* __restrict__ Wt,
    const float* __restrict__ avs, const float* __restrict__ avd,
    _Float16* __restrict__ Hh,          // head-major [4][N][32]
    float* __restrict__ alpha_s, float* __restrict__ alpha_d, int nrows)
{
    __shared__ _Float16 Xs[64 * GP];    // 17.0 KB
    __shared__ _Float16 Ws[128 * GP];   // 34.0 KB

    int t = threadIdx.x;
    int brow = blockIdx.x * 64;

    // stage A rows: thread t -> row t>>2, 32-feature chunk q = t&3 (= head q)
    {
        int r = t >> 2, q = t & 3;
        int grow = brow + r;
        _Float16* d = Xs + r * GP + q * 32;
        if (F32IN) {
            const float* A32 = (const float*)Ain;
            float4 v[8];
#pragma unroll
            for (int j = 0; j < 8; ++j) v[j] = make_float4(0, 0, 0, 0);
            if (grow < nrows) {
                const float4* p = (const float4*)(A32 + (size_t)grow * 128 + q * 32);
#pragma unroll
                for (int j = 0; j < 8; ++j) v[j] = p[j];
            }
#pragma unroll
            for (int j = 0; j < 8; ++j) {
                half4 h = {(_Float16)v[j].x, (_Float16)v[j].y,
                           (_Float16)v[j].z, (_Float16)v[j].w};
                *(half4*)(d + j * 4) = h;
            }
        } else {
            const _Float16* A16 = (const _Float16*)Ain;  // head-major
            half8 v0 = {}, v1 = {}, v2 = {}, v3 = {};
            if (grow < nrows) {
                const half8* p = (const half8*)(A16 + (size_t)q * HSZ + (size_t)grow * 32);
                v0 = p[0]; v1 = p[1]; v2 = p[2]; v3 = p[3];
            }
            *(half8*)(d + 0)  = v0; *(half8*)(d + 8)  = v1;
            *(half8*)(d + 16) = v2; *(half8*)(d + 24) = v3;
        }
    }
    // stage Wt (128 x 256B = 32KB): thread t -> row t>>1, 128B half t&1
    {
        int wr = t >> 1, wh = t & 1;
        const half8* p = (const half8*)(Wt + wr * 128 + wh * 64);
        _Float16* d = Ws + wr * GP + wh * 64;
#pragma unroll
        for (int j = 0; j < 8; ++j) *(half8*)(d + j * 8) = p[j];
    }
    __syncthreads();

    int wv = t >> 6, l = t & 63;
    int lrow = l & 15;
    int lk8  = (l >> 4) * 8;

    f32x4 acc[8];
#pragma unroll
    for (int n = 0; n < 8; ++n) acc[n] = (f32x4){0.f, 0.f, 0.f, 0.f};

    const _Float16* xbase = Xs + (wv * 16 + lrow) * GP + lk8;
#pragma unroll
    for (int kk = 0; kk < 4; ++kk) {
        half8 a = *(const half8*)(xbase + kk * 32);
#pragma unroll
        for (int n = 0; n < 8; ++n) {
            half8 bf = *(const half8*)(Ws + (n * 16 + lrow) * GP + kk * 32 + lk8);
            acc[n] = __builtin_amdgcn_mfma_f32_16x16x32_f16(a, bf, acc[n], 0, 0, 0);
        }
    }

    // epilogue: head-major h16 stores + fused alpha dot products
    int c = lrow;
    int g = l >> 4;
#pragma unroll
    for (int n = 0; n < 8; ++n) {
        int head = n >> 1;
        int off  = (n & 1) * 16 + c;     // feature within head, 0..31
#pragma unroll
        for (int r = 0; r < 4; ++r) {
            int row = brow + wv * 16 + g * 4 + r;
            if (row < nrows)
                Hh[(size_t)head * HSZ + (size_t)row * 32 + off] = (_Float16)acc[n][r];
        }
    }
#pragma unroll
    for (int hd = 0; hd < 4; ++hd) {
        float as0 = avs[hd * 32 + c], as1 = avs[hd * 32 + 16 + c];
        float ad0 = avd[hd * 32 + c], ad1 = avd[hd * 32 + 16 + c];
#pragma unroll
        for (int r = 0; r < 4; ++r) {
            float ps = acc[2 * hd][r] * as0 + acc[2 * hd + 1][r] * as1;
            float pd = acc[2 * hd][r] * ad0 + acc[2 * hd + 1][r] * ad1;
            ps += __shfl_xor(ps, 1); ps += __shfl_xor(ps, 2);
            ps += __shfl_xor(ps, 4); ps += __shfl_xor(ps, 8);
            pd += __shfl_xor(pd, 1); pd += __shfl_xor(pd, 2);
            pd += __shfl_xor(pd, 4); pd += __shfl_xor(pd, 8);
            if (c == 0) {
                int row = brow + wv * 16 + g * 4 + r;
                if (row < nrows) {
                    alpha_s[row * 4 + hd] = ps;
                    alpha_d[row * 4 + hd] = pd;
                }
            }
        }
    }
}

// ------- fused attention + gather, HEAD-SHARDED (XCD-affine) ---------------
// Block (ngrp, head = blk&3): with round-robin blockIdx->XCD dispatch, head k
// runs on XCDs {k, k+4}; per-XCD h working set = head slice 3.2MB + alpha
// 0.8MB -> L2-resident. Wave = (node, head); p = lane>>2 strides edges by 16,
// lane owns 8 features (ftl = lane&3, 4 lanes x half8 = 64B/edge). exp shared
// per lane-quad (not replicated across heads - each head needs its own).
// Reduction: 4 shfl_xor stages over lane bits 2..5.
template <bool F16OUT>
__global__ __launch_bounds__(256) void att_gather_kernel(
    const unsigned short* __restrict__ csr_src, const int2* __restrict__ node_info,
    const float* __restrict__ alpha_s, const float* __restrict__ alpha_d,
    const _Float16* __restrict__ hbuf,   // head-major [4][N][32]
    const float* __restrict__ b,
    float* __restrict__ out32,           // row-major [N][128]
    _Float16* __restrict__ out16)        // head-major [4][N][32]
{
    int blk = blockIdx.x;
    int hh  = blk & 3;                   // head (XCD-sharded)
    int node = (blk >> 2) * 4 + (threadIdx.x >> 6);
    int lane = threadIdx.x & 63;
    int p   = lane >> 2;                 // edge parity 0..15
    int ftl = lane & 3;                  // feature quad
    int f   = ftl * 8;                   // feature offset within head
    int2 bi = node_info[node];
    int beg = bi.x, end = bi.x + bi.y;
    float ad = alpha_d[node * 4 + hh];
    const _Float16* hb = hbuf + (size_t)hh * HSZ;

    float acc[8] = {0.f, 0.f, 0.f, 0.f, 0.f, 0.f, 0.f, 0.f};
    float den = 0.f;
    int i = beg + p;
    for (; i + 16 < end; i += 32) {      // 2 independent edges per lane/iter
        int s0 = csr_src[i];
        int s1 = csr_src[i + 16];
        float l0 = alpha_s[s0 * 4 + hh] + ad;
        float l1 = alpha_s[s1 * 4 + hh] + ad;
        half8 h0 = *(const half8*)(hb + (size_t)s0 * 32 + f);
        half8 h1 = *(const half8*)(hb + (size_t)s1 * 32 + f);
        l0 = fmaxf(l0, 0.2f * l0);
        l1 = fmaxf(l1, 0.2f * l1);
        float e0 = __expf(l0);
        float e1 = __expf(l1);
        den += e0 + e1;
#pragma unroll
        for (int j = 0; j < 8; ++j) acc[j] = fmaf(e0, (float)h0[j], acc[j]);
#pragma unroll
        for (int j = 0; j < 8; ++j) acc[j] = fmaf(e1, (float)h1[j], acc[j]);
    }
    if (i < end) {                       // tail: one edge of this parity
        int s0 = csr_src[i];
        float l0 = alpha_s[s0 * 4 + hh] + ad;
        half8 h0 = *(const half8*)(hb + (size_t)s0 * 32 + f);
        l0 = fmaxf(l0, 0.2f * l0);
        float e0 = __expf(l0);
        den += e0;
#pragma unroll
        for (int j = 0; j < 8; ++j) acc[j] = fmaf(e0, (float)h0[j], acc[j]);
    }

    // combine the 16 parities (lane bits 2..5)
#pragma unroll
    for (int off = 4; off < 64; off <<= 1) {
#pragma unroll
        for (int j = 0; j < 8; ++j) acc[j] += __shfl_xor(acc[j], off);
        den += __shfl_xor(den, off);
    }

    if (p == 0) {
        float rd = 1.f / fmaxf(den, 1e-16f);
        const float* bp = b + hh * 32 + f;
        float x[8];
#pragma unroll
        for (int j = 0; j < 8; ++j) {
            x[j] = acc[j] * rd + bp[j];
            x[j] = (x[j] > 0.f) ? x[j] : expm1f(x[j]);
        }
        if (F16OUT) {
            half8 hv;
#pragma unroll
            for (int j = 0; j < 8; ++j) hv[j] = (_Float16)x[j];
            *(half8*)(out16 + (size_t)hh * HSZ + (size_t)node * 32 + f) = hv;
        } else {
            float* op = out32 + (size_t)node * 128 + hh * 32 + f;
            *(float4*)op       = make_float4(x[0], x[1], x[2], x[3]);
            *(float4*)(op + 4) = make_float4(x[4], x[5], x[6], x[7]);
        }
    }
}

extern "C" void kernel_launch(void* const* d_in, const int* in_sizes, int n_in,
                              void* d_out, int out_size, void* d_ws, size_t ws_size,
                              hipStream_t stream) {
    const float* X    = (const float*)d_in[0];
    const int*   ei   = (const int*)d_in[1];
    const float* W0   = (const float*)d_in[2];
    const float* as0  = (const float*)d_in[3];
    const float* ad0  = (const float*)d_in[4];
    const float* b0   = (const float*)d_in[5];
    const float* W1   = (const float*)d_in[6];
    const float* as1  = (const float*)d_in[7];
    const float* ad1  = (const float*)d_in[8];
    const float* b1   = (const float*)d_in[9];

    const int* srcp = ei;            // edge_index[0]
    const int* dstp = ei + NEDGES;   // edge_index[1]

    _Float16* h16  = (_Float16*)d_ws;            // 6.4M halves, head-major
    _Float16* ho16 = h16 + 4 * HSZ;              // 6.4M halves, head-major
    _Float16* W0t  = ho16 + 4 * HSZ;             // 16384
    _Float16* W1t  = W0t + 16384;                // 16384
    float* as_ = (float*)(W1t + 16384);          // 200,000
    float* ad_ = as_ + 200000;                   // 200,000
    unsigned* binned = (unsigned*)(ad_ + 200000);            // (KB+1)*CAPB
    unsigned short* csr_src = (unsigned short*)(binned + (KB + 1) * CAPB);
    int2* node_info = (int2*)(csr_src + ((KB * CAPB + 1) & ~1));  // 50,000
    int*  bincur    = (int*)(node_info + NNODES);                 // KB

    // ---- CSR build (two-pass LDS binning), layer-invariant ----
    bininit_kernel<<<1, 256, 0, stream>>>(bincur);
    binA_kernel<<<NABLK, 256, 0, stream>>>(srcp, dstp, bincur, binned);
    binB_kernel<<<KB, 256, 0, stream>>>(binned, bincur, csr_src, node_info);

    // ---- W transposes to fp16 ----
    prepw_kernel<<<64, 256, 0, stream>>>(W0, W1, W0t, W1t);

    const int ATT_BLOCKS  = (NNODES / 4) * 4;    // (node-group, head)
    const int GEMM_BLOCKS = (NNODES + 63) / 64;

    // layer 0 (fp32 input, converted in staging)
    gemm_mfma_kernel<true><<<GEMM_BLOCKS, 256, 0, stream>>>(
        X, W0t, as0, ad0, h16, as_, ad_, NNODES);
    att_gather_kernel<true><<<ATT_BLOCKS, 256, 0, stream>>>(
        csr_src, node_info, as_, ad_, h16, b0, nullptr, ho16);

    // layer 1 (fp16 head-major input from layer-0 output)
    gemm_mfma_kernel<false><<<GEMM_BLOCKS, 256, 0, stream>>>(
        ho16, W1t, as1, ad1, h16, as_, ad_, NNODES);
    att_gather_kernel<false><<<ATT_BLOCKS, 256, 0, stream>>>(
        csr_src, node_info, as_, ad_, h16, b1, (float*)d_out, nullptr);
}

// Round 15
// 153.015 us; speedup vs baseline: 2.1503x; 2.1503x over previous
//
#include <hip/hip_runtime.h>
#include <math.h>
#include <float.h>

#define NNODES 50000
#define NEDGES 800000
// feature dims: in=hid=out=128, heads=4, head_dim=32

// ---- CSR binning params ----
#define KB    196                       // coarse bins (dst>>8), covers 50176 nodes
#define NPB   256                       // nodes per bin
#define CAPB  4608                      // per-bin capacity (mean 4081, +8 sigma)
#define EPB   4096                      // edges per pass-A block
#define NABLK ((NEDGES + EPB - 1) / EPB)   // 196

typedef __attribute__((ext_vector_type(4))) _Float16 half4;
typedef __attribute__((ext_vector_type(8))) _Float16 half8;
typedef __attribute__((ext_vector_type(4))) float f32x4;

// ---------------- setup: bincur init + W0/W1 -> fp16 transposed ------------
__global__ __launch_bounds__(256) void setup_kernel(
    const float* __restrict__ W0, const float* __restrict__ W1,
    _Float16* __restrict__ W0t, _Float16* __restrict__ W1t,
    int* __restrict__ bincur)
{
    int idx = blockIdx.x * 256 + threadIdx.x;
    if (idx < KB) bincur[idx] = idx * CAPB;
    if (idx < 128 * 128) {
        int cc = idx >> 7, k = idx & 127;
        W0t[idx] = (_Float16)W0[k * 128 + cc];
        W1t[idx] = (_Float16)W1[k * 128 + cc];
    }
}

// ---------------- CSR build, two-pass LDS binning ----------------
__global__ __launch_bounds__(256) void binA_kernel(
    const int* __restrict__ src, const int* __restrict__ dst,
    int* __restrict__ bincur, unsigned* __restrict__ binned)
{
    __shared__ int lhist[KB];
    __shared__ int lstart[KB];
    __shared__ int lcur[KB];
    __shared__ int gbase[KB];
    __shared__ unsigned lbuf[EPB];
    __shared__ int wtot[4];

    int t = threadIdx.x;
    int e0 = blockIdx.x * EPB;
    int ecnt = NEDGES - e0; if (ecnt > EPB) ecnt = EPB;

    for (int b = t; b < KB; b += 256) lhist[b] = 0;
    __syncthreads();

    for (int idx = t; idx < ecnt; idx += 256)
        atomicAdd(&lhist[((unsigned)dst[e0 + idx]) >> 8], 1);
    __syncthreads();

    {
        int lane = t & 63, w = t >> 6;
        int v = (t < KB) ? lhist[t] : 0;
        int x = v;
#pragma unroll
        for (int off = 1; off < 64; off <<= 1) {
            int y = __shfl_up(x, off, 64);
            if (lane >= off) x += y;
        }
        if (lane == 63) wtot[w] = x;
        __syncthreads();
        int wpre = 0;
#pragma unroll
        for (int j = 0; j < 4; ++j) if (j < w) wpre += wtot[j];
        int ex = wpre + x - v;
        if (t < KB) { lstart[t] = ex; lcur[t] = ex; }
    }
    __syncthreads();

    if (t < KB) {
        int c = lhist[t];
        gbase[t] = c ? atomicAdd(&bincur[t], c) : 0;
    }
    __syncthreads();

    for (int idx = t; idx < ecnt; idx += 256) {
        unsigned d = (unsigned)dst[e0 + idx];
        unsigned s = (unsigned)src[e0 + idx];
        int pos = atomicAdd(&lcur[d >> 8], 1);
        lbuf[pos] = (d << 16) | s;
    }
    __syncthreads();

    for (int idx = t; idx < ecnt; idx += 256) {
        unsigned p = lbuf[idx];
        int b = p >> 24;
        binned[gbase[b] + (idx - lstart[b])] = p;
    }
}

__global__ __launch_bounds__(256) void binB_kernel(
    const unsigned* __restrict__ binned, const int* __restrict__ bincur,
    unsigned short* __restrict__ csr_src, int2* __restrict__ node_info)
{
    __shared__ int lhist[NPB];
    __shared__ int lcur[NPB];
    __shared__ int wtot[4];
    int k = blockIdx.x;
    int t = threadIdx.x;
    int base = k * CAPB;
    int cnt = bincur[k] - base;

    lhist[t] = 0;
    __syncthreads();

    for (int i = t; i < cnt; i += 256)
        atomicAdd(&lhist[(binned[base + i] >> 16) & 0xFF], 1);
    __syncthreads();

    int lane = t & 63, w = t >> 6;
    int v = lhist[t];
    int x = v;
#pragma unroll
    for (int off = 1; off < 64; off <<= 1) {
        int y = __shfl_up(x, off, 64);
        if (lane >= off) x += y;
    }
    if (lane == 63) wtot[w] = x;
    __syncthreads();
    int wpre = 0;
#pragma unroll
    for (int j = 0; j < 4; ++j) if (j < w) wpre += wtot[j];
    int ex = wpre + x - v;
    lcur[t] = ex;
    int node = k * NPB + t;
    if (node < NNODES) node_info[node] = make_int2(base + ex, v);
    __syncthreads();

    for (int i = t; i < cnt; i += 256) {
        unsigned p = binned[base + i];
        int ln = (p >> 16) & 0xFF;
        int pos = atomicAdd(&lcur[ln], 1);
        csr_src[base + pos] = (unsigned short)(p & 0xFFFFu);
    }
}

// ---------------- MFMA GEMM + alpha: h = A@W ; alpha_s/d = <h, a_*> -------
// A [nrows][128] fp32 (layer 0, converted during staging) or fp16 (layer 1);
// Wt fp16 [128 cols][128 k]. Block = 256 thr = 4 waves; tile 64 x 128.
// v_mfma_f32_16x16x32_f16 frag mapping verified in round 12 (absmax parity).
#define GP 136
template <bool F32IN>
__global__ __launch_bounds__(256) void gemm_mfma_kernel(
    const void* __restrict__ Ain, const _Float16* __restrict__ Wt,
    const float* __restrict__ avs, const float* __restrict__ avd,
    _Float16* __restrict__ Hh, float* __restrict__ alpha_s,
    float* __restrict__ alpha_d, int nrows)
{
    __shared__ _Float16 Xs[64 * GP];    // 17.0 KB
    __shared__ _Float16 Ws[128 * GP];   // 34.0 KB

    int t = threadIdx.x;
    int brow = blockIdx.x * 64;

    // stage A rows: thread t -> row t>>2, 32-element chunk q = t&3
    {
        int r = t >> 2, q = t & 3;
        int grow = brow + r;
        _Float16* d = Xs + r * GP + q * 32;
        if (F32IN) {
            const float* A32 = (const float*)Ain;
            float4 v[8];
#pragma unroll
            for (int j = 0; j < 8; ++j) v[j] = make_float4(0, 0, 0, 0);
            if (grow < nrows) {
                const float4* p = (const float4*)(A32 + (size_t)grow * 128 + q * 32);
#pragma unroll
                for (int j = 0; j < 8; ++j) v[j] = p[j];
            }
#pragma unroll
            for (int j = 0; j < 8; ++j) {
                half4 h = {(_Float16)v[j].x, (_Float16)v[j].y,
                           (_Float16)v[j].z, (_Float16)v[j].w};
                *(half4*)(d + j * 4) = h;
            }
        } else {
            const _Float16* A16 = (const _Float16*)Ain;
            half8 v0 = {}, v1 = {}, v2 = {}, v3 = {};
            if (grow < nrows) {
                const half8* p = (const half8*)(A16 + (size_t)grow * 128 + q * 32);
                v0 = p[0]; v1 = p[1]; v2 = p[2]; v3 = p[3];
            }
            *(half8*)(d + 0)  = v0; *(half8*)(d + 8)  = v1;
            *(half8*)(d + 16) = v2; *(half8*)(d + 24) = v3;
        }
    }
    // stage Wt (128 x 256B = 32KB): thread t -> row t>>1, 128B half t&1
    {
        int wr = t >> 1, wh = t & 1;
        const half8* p = (const half8*)(Wt + wr * 128 + wh * 64);
        _Float16* d = Ws + wr * GP + wh * 64;
#pragma unroll
        for (int j = 0; j < 8; ++j) *(half8*)(d + j * 8) = p[j];
    }
    __syncthreads();

    int wv = t >> 6, l = t & 63;
    int lrow = l & 15;
    int lk8  = (l >> 4) * 8;

    f32x4 acc[8];
#pragma unroll
    for (int n = 0; n < 8; ++n) acc[n] = (f32x4){0.f, 0.f, 0.f, 0.f};

    const _Float16* xbase = Xs + (wv * 16 + lrow) * GP + lk8;
#pragma unroll
    for (int kk = 0; kk < 4; ++kk) {
        half8 a = *(const half8*)(xbase + kk * 32);
#pragma unroll
        for (int n = 0; n < 8; ++n) {
            half8 bf = *(const half8*)(Ws + (n * 16 + lrow) * GP + kk * 32 + lk8);
            acc[n] = __builtin_amdgcn_mfma_f32_16x16x32_f16(a, bf, acc[n], 0, 0, 0);
        }
    }

    // epilogue: h16 stores + fused alpha dot products
    int c = lrow;
    int g = l >> 4;
#pragma unroll
    for (int n = 0; n < 8; ++n) {
#pragma unroll
        for (int r = 0; r < 4; ++r) {
            int row = brow + wv * 16 + g * 4 + r;
            if (row < nrows)
                Hh[(size_t)row * 128 + n * 16 + c] = (_Float16)acc[n][r];
        }
    }
#pragma unroll
    for (int hd = 0; hd < 4; ++hd) {
        float as0 = avs[hd * 32 + c], as1 = avs[hd * 32 + 16 + c];
        float ad0 = avd[hd * 32 + c], ad1 = avd[hd * 32 + 16 + c];
#pragma unroll
        for (int r = 0; r < 4; ++r) {
            float ps = acc[2 * hd][r] * as0 + acc[2 * hd + 1][r] * as1;
            float pd = acc[2 * hd][r] * ad0 + acc[2 * hd + 1][r] * ad1;
            ps += __shfl_xor(ps, 1); ps += __shfl_xor(ps, 2);
            ps += __shfl_xor(ps, 4); ps += __shfl_xor(ps, 8);
            pd += __shfl_xor(pd, 1); pd += __shfl_xor(pd, 2);
            pd += __shfl_xor(pd, 4); pd += __shfl_xor(pd, 8);
            if (c == 0) {
                int row = brow + wv * 16 + g * 4 + r;
                if (row < nrows) {
                    alpha_s[row * 4 + hd] = ps;
                    alpha_d[row * 4 + hd] = pd;
                }
            }
        }
    }
}

// ------- fused attention + gather: 4 edge parities x 16 feature lanes ------
// (round-13 structure: best measured). One wave per node; p = lane>>4 strides
// edges by 4; lane owns 8 features (ft = lane&15): 16 lanes x 16B = full 256B
// fp16 h row per edge. csr_src is ushort (src < 65536). No max-shift (logits
// O(+-6), exp fp32-safe, softmax shift-invariant). Parity partials combined
// via shfl_xor(16)+shfl_xor(32).
template <bool F16OUT>
__global__ __launch_bounds__(256) void att_gather_kernel(
    const unsigned short* __restrict__ csr_src, const int2* __restrict__ node_info,
    const float* __restrict__ alpha_s, const float* __restrict__ alpha_d,
    const _Float16* __restrict__ hbuf, const float* __restrict__ b,
    float* __restrict__ out32, _Float16* __restrict__ out16)
{
    int node = blockIdx.x * 4 + (threadIdx.x >> 6);
    if (node >= NNODES) return;
    int lane = threadIdx.x & 63;
    int p  = lane >> 4;                 // edge parity 0..3
    int ft = lane & 15;                 // feature block
    int f  = ft * 8;                    // features f..f+7
    int hh = ft >> 2;                   // head
    int2 bi = node_info[node];
    int beg = bi.x, end = bi.x + bi.y;
    float ad = alpha_d[node * 4 + hh];

    float acc[8] = {0.f, 0.f, 0.f, 0.f, 0.f, 0.f, 0.f, 0.f};
    float den = 0.f;
    int i = beg + p;
    for (; i + 4 < end; i += 8) {       // 2 independent edges per lane/iter
        int s0 = csr_src[i];
        int s1 = csr_src[i + 4];
        float l0 = alpha_s[s0 * 4 + hh] + ad;
        float l1 = alpha_s[s1 * 4 + hh] + ad;
        half8 h0 = *(const half8*)(hbuf + (size_t)s0 * 128 + f);
        half8 h1 = *(const half8*)(hbuf + (size_t)s1 * 128 + f);
        l0 = fmaxf(l0, 0.2f * l0);      // leaky relu
        l1 = fmaxf(l1, 0.2f * l1);
        float e0 = __expf(l0);
        float e1 = __expf(l1);
        den += e0 + e1;
#pragma unroll
        for (int j = 0; j < 8; ++j) acc[j] = fmaf(e0, (float)h0[j], acc[j]);
#pragma unroll
        for (int j = 0; j < 8; ++j) acc[j] = fmaf(e1, (float)h1[j], acc[j]);
    }
    for (; i < end; i += 4) {           // tail: 0 or 1 edge of this parity
        int s0 = csr_src[i];
        float l0 = alpha_s[s0 * 4 + hh] + ad;
        half8 h0 = *(const half8*)(hbuf + (size_t)s0 * 128 + f);
        l0 = fmaxf(l0, 0.2f * l0);
        float e0 = __expf(l0);
        den += e0;
#pragma unroll
        for (int j = 0; j < 8; ++j) acc[j] = fmaf(e0, (float)h0[j], acc[j]);
    }

    // combine the 4 parities (lane bits 4,5)
#pragma unroll
    for (int j = 0; j < 8; ++j) {
        acc[j] += __shfl_xor(acc[j], 16);
        acc[j] += __shfl_xor(acc[j], 32);
    }
    den += __shfl_xor(den, 16);
    den += __shfl_xor(den, 32);

    if (p == 0) {
        float rd = 1.f / fmaxf(den, 1e-16f);
        float4 bv0 = *(const float4*)(b + f);
        float4 bv1 = *(const float4*)(b + f + 4);
        float x[8];
        x[0] = acc[0] * rd + bv0.x; x[1] = acc[1] * rd + bv0.y;
        x[2] = acc[2] * rd + bv0.z; x[3] = acc[3] * rd + bv0.w;
        x[4] = acc[4] * rd + bv1.x; x[5] = acc[5] * rd + bv1.y;
        x[6] = acc[6] * rd + bv1.z; x[7] = acc[7] * rd + bv1.w;
#pragma unroll
        for (int j = 0; j < 8; ++j) x[j] = (x[j] > 0.f) ? x[j] : expm1f(x[j]);
        if (F16OUT) {
            half8 hv;
#pragma unroll
            for (int j = 0; j < 8; ++j) hv[j] = (_Float16)x[j];
            *(half8*)(out16 + (size_t)node * 128 + f) = hv;
        } else {
            *(float4*)(out32 + (size_t)node * 128 + f) =
                make_float4(x[0], x[1], x[2], x[3]);
            *(float4*)(out32 + (size_t)node * 128 + f + 4) =
                make_float4(x[4], x[5], x[6], x[7]);
        }
    }
}

extern "C" void kernel_launch(void* const* d_in, const int* in_sizes, int n_in,
                              void* d_out, int out_size, void* d_ws, size_t ws_size,
                              hipStream_t stream) {
    const float* X    = (const float*)d_in[0];
    const int*   ei   = (const int*)d_in[1];
    const float* W0   = (const float*)d_in[2];
    const float* as0  = (const float*)d_in[3];
    const float* ad0  = (const float*)d_in[4];
    const float* b0   = (const float*)d_in[5];
    const float* W1   = (const float*)d_in[6];
    const float* as1  = (const float*)d_in[7];
    const float* ad1  = (const float*)d_in[8];
    const float* b1   = (const float*)d_in[9];

    const int* srcp = ei;            // edge_index[0]
    const int* dstp = ei + NEDGES;   // edge_index[1]

    _Float16* h16  = (_Float16*)d_ws;            // 6.4M halves
    _Float16* ho16 = h16 + 6400000;              // 6.4M halves (layer-1 out)
    _Float16* W0t  = ho16 + 6400000;             // 16384
    _Float16* W1t  = W0t + 16384;                // 16384
    float* as_ = (float*)(W1t + 16384);          // 200,000
    float* ad_ = as_ + 200000;                   // 200,000
    unsigned* binned = (unsigned*)(ad_ + 200000);            // (KB+1)*CAPB
    unsigned short* csr_src = (unsigned short*)(binned + (KB + 1) * CAPB);
    int2* node_info = (int2*)(csr_src + ((KB * CAPB + 1) & ~1));  // 50,000
    int*  bincur    = (int*)(node_info + NNODES);                 // KB

    // ---- setup (bincur init + W transposes) + CSR build, layer-invariant --
    setup_kernel<<<64, 256, 0, stream>>>(W0, W1, W0t, W1t, bincur);
    binA_kernel<<<NABLK, 256, 0, stream>>>(srcp, dstp, bincur, binned);
    binB_kernel<<<KB, 256, 0, stream>>>(binned, bincur, csr_src, node_info);

    const int NODE_BLOCKS = (NNODES + 3) / 4;
    const int GEMM_BLOCKS = (NNODES + 63) / 64;

    // layer 0 (fp32 input, converted in staging)
    gemm_mfma_kernel<true><<<GEMM_BLOCKS, 256, 0, stream>>>(
        X, W0t, as0, ad0, h16, as_, ad_, NNODES);
    att_gather_kernel<true><<<NODE_BLOCKS, 256, 0, stream>>>(
        csr_src, node_info, as_, ad_, h16, b0, nullptr, ho16);

    // layer 1 (fp16 input from layer-0 output)
    gemm_mfma_kernel<false><<<GEMM_BLOCKS, 256, 0, stream>>>(
        ho16, W1t, as1, ad1, h16, as_, ad_, NNODES);
    att_gather_kernel<false><<<NODE_BLOCKS, 256, 0, stream>>>(
        csr_src, node_info, as_, ad_, h16, b1, (float*)d_out, nullptr);
}

// Round 16
// 146.939 us; speedup vs baseline: 2.2392x; 1.0413x over previous
//
#include <hip/hip_runtime.h>
#include <math.h>
#include <float.h>

#define NNODES 50000
#define NEDGES 800000
// feature dims: in=hid=out=128, heads=4, head_dim=32

// ---- CSR binning params ----
#define KB    196                       // coarse bins (dst>>8), covers 50176 nodes
#define NPB   256                       // nodes per bin
#define CAPB  4608                      // per-bin capacity (mean 4081, +8 sigma)
#define EPB   4096                      // edges per pass-A block
#define NABLK ((NEDGES + EPB - 1) / EPB)   // 196
#define RB    18                        // binB reg-stage capacity (CAPB/256)

typedef __attribute__((ext_vector_type(4))) _Float16 half4;
typedef __attribute__((ext_vector_type(8))) _Float16 half8;
typedef __attribute__((ext_vector_type(4))) float f32x4;

// ---------------- setup: bincur init + W0/W1 -> fp16 transposed ------------
__global__ __launch_bounds__(256) void setup_kernel(
    const float* __restrict__ W0, const float* __restrict__ W1,
    _Float16* __restrict__ W0t, _Float16* __restrict__ W1t,
    int* __restrict__ bincur)
{
    int idx = blockIdx.x * 256 + threadIdx.x;
    if (idx < KB) bincur[idx] = idx * CAPB;
    if (idx < 128 * 128) {
        int cc = idx >> 7, k = idx & 127;
        W0t[idx] = (_Float16)W0[k * 128 + cc];
        W1t[idx] = (_Float16)W1[k * 128 + cc];
    }
}

// ---------------- CSR build, two-pass LDS binning (register-staged) --------
// Pass A: each thread loads its 16 edges ONCE into registers; hist -> scan ->
// LDS place -> contiguous per-bin global writes (one atomicAdd reserves each
// (block,bin) run). No second global read.
__global__ __launch_bounds__(256) void binA_kernel(
    const int* __restrict__ src, const int* __restrict__ dst,
    int* __restrict__ bincur, unsigned* __restrict__ binned)
{
    __shared__ int lhist[KB];
    __shared__ int lstart[KB];
    __shared__ int lcur[KB];
    __shared__ int gbase[KB];
    __shared__ unsigned lbuf[EPB];
    __shared__ int wtot[4];

    int t = threadIdx.x;
    int e0 = blockIdx.x * EPB;
    int ecnt = NEDGES - e0; if (ecnt > EPB) ecnt = EPB;
    int nk = (ecnt - t + 255) >> 8;      // this thread's edge count
    if (nk < 0) nk = 0;

    // load edges once (coalesced: edge e0 + t + 256k)
    unsigned pk[16];
#pragma unroll
    for (int k = 0; k < 16; ++k) {
        if (k < nk) {
            int e = e0 + t + (k << 8);
            pk[k] = (((unsigned)dst[e]) << 16) | (unsigned)src[e];
        }
    }

    for (int b = t; b < KB; b += 256) lhist[b] = 0;
    __syncthreads();

#pragma unroll
    for (int k = 0; k < 16; ++k)
        if (k < nk) atomicAdd(&lhist[pk[k] >> 24], 1);
    __syncthreads();

    // exclusive scan of lhist[0..KB)
    {
        int lane = t & 63, w = t >> 6;
        int v = (t < KB) ? lhist[t] : 0;
        int x = v;
#pragma unroll
        for (int off = 1; off < 64; off <<= 1) {
            int y = __shfl_up(x, off, 64);
            if (lane >= off) x += y;
        }
        if (lane == 63) wtot[w] = x;
        __syncthreads();
        int wpre = 0;
#pragma unroll
        for (int j = 0; j < 4; ++j) if (j < w) wpre += wtot[j];
        int ex = wpre + x - v;
        if (t < KB) { lstart[t] = ex; lcur[t] = ex; }
    }
    __syncthreads();

    if (t < KB) {
        int c = lhist[t];
        gbase[t] = c ? atomicAdd(&bincur[t], c) : 0;
    }
    __syncthreads();

    // place into LDS grouped by bin (from registers)
#pragma unroll
    for (int k = 0; k < 16; ++k) {
        if (k < nk) {
            int pos = atomicAdd(&lcur[pk[k] >> 24], 1);
            lbuf[pos] = pk[k];
        }
    }
    __syncthreads();

    // copy out: contiguous per-bin runs
    for (int idx = t; idx < ecnt; idx += 256) {
        unsigned p = lbuf[idx];
        int b = p >> 24;
        binned[gbase[b] + (idx - lstart[b])] = p;
    }
}

// Pass B: block k owns bin k (nodes k*256..+255). Register-stage the bin's
// edges (single read), local hist+scan, scatter into this block's private
// CAP-padded csr region; emit node_info = (beg, deg).
__global__ __launch_bounds__(256) void binB_kernel(
    const unsigned* __restrict__ binned, const int* __restrict__ bincur,
    unsigned short* __restrict__ csr_src, int2* __restrict__ node_info)
{
    __shared__ int lhist[NPB];
    __shared__ int lcur[NPB];
    __shared__ int wtot[4];
    int k = blockIdx.x;
    int t = threadIdx.x;
    int base = k * CAPB;
    int cnt = bincur[k] - base;
    int nk = (cnt - t + 255) >> 8;
    if (nk < 0) nk = 0;

    unsigned pk[RB];
#pragma unroll
    for (int j = 0; j < RB; ++j)
        if (j < nk) pk[j] = binned[base + t + (j << 8)];

    lhist[t] = 0;
    __syncthreads();

#pragma unroll
    for (int j = 0; j < RB; ++j)
        if (j < nk) atomicAdd(&lhist[(pk[j] >> 16) & 0xFF], 1);
    __syncthreads();

    int lane = t & 63, w = t >> 6;
    int v = lhist[t];
    int x = v;
#pragma unroll
    for (int off = 1; off < 64; off <<= 1) {
        int y = __shfl_up(x, off, 64);
        if (lane >= off) x += y;
    }
    if (lane == 63) wtot[w] = x;
    __syncthreads();
    int wpre = 0;
#pragma unroll
    for (int j = 0; j < 4; ++j) if (j < w) wpre += wtot[j];
    int ex = wpre + x - v;
    lcur[t] = ex;
    int node = k * NPB + t;
    if (node < NNODES) node_info[node] = make_int2(base + ex, v);
    __syncthreads();

#pragma unroll
    for (int j = 0; j < RB; ++j) {
        if (j < nk) {
            int ln = (pk[j] >> 16) & 0xFF;
            int pos = atomicAdd(&lcur[ln], 1);
            csr_src[base + pos] = (unsigned short)(pk[j] & 0xFFFFu);
        }
    }
}

// ---------------- MFMA GEMM + alpha: h = A@W ; alpha_s/d = <h, a_*> -------
// A [nrows][128] fp32 (layer 0, converted during staging) or fp16 (layer 1);
// Wt fp16 [128 cols][128 k]. Block = 256 thr = 4 waves; tile 64 x 128.
// v_mfma_f32_16x16x32_f16 frag mapping verified in round 12 (absmax parity).
#define GP 136
template <bool F32IN>
__global__ __launch_bounds__(256) void gemm_mfma_kernel(
    const void* __restrict__ Ain, const _Float16* __restrict__ Wt,
    const float* __restrict__ avs, const float* __restrict__ avd,
    _Float16* __restrict__ Hh, float* __restrict__ alpha_s,
    float* __restrict__ alpha_d, int nrows)
{
    __shared__ _Float16 Xs[64 * GP];    // 17.0 KB
    __shared__ _Float16 Ws[128 * GP];   // 34.0 KB

    int t = threadIdx.x;
    int brow = blockIdx.x * 64;

    // stage A rows: thread t -> row t>>2, 32-element chunk q = t&3
    {
        int r = t >> 2, q = t & 3;
        int grow = brow + r;
        _Float16* d = Xs + r * GP + q * 32;
        if (F32IN) {
            const float* A32 = (const float*)Ain;
            float4 v[8];
#pragma unroll
            for (int j = 0; j < 8; ++j) v[j] = make_float4(0, 0, 0, 0);
            if (grow < nrows) {
                const float4* p = (const float4*)(A32 + (size_t)grow * 128 + q * 32);
#pragma unroll
                for (int j = 0; j < 8; ++j) v[j] = p[j];
            }
#pragma unroll
            for (int j = 0; j < 8; ++j) {
                half4 h = {(_Float16)v[j].x, (_Float16)v[j].y,
                           (_Float16)v[j].z, (_Float16)v[j].w};
                *(half4*)(d + j * 4) = h;
            }
        } else {
            const _Float16* A16 = (const _Float16*)Ain;
            half8 v0 = {}, v1 = {}, v2 = {}, v3 = {};
            if (grow < nrows) {
                const half8* p = (const half8*)(A16 + (size_t)grow * 128 + q * 32);
                v0 = p[0]; v1 = p[1]; v2 = p[2]; v3 = p[3];
            }
            *(half8*)(d + 0)  = v0; *(half8*)(d + 8)  = v1;
            *(half8*)(d + 16) = v2; *(half8*)(d + 24) = v3;
        }
    }
    // stage Wt (128 x 256B = 32KB): thread t -> row t>>1, 128B half t&1
    {
        int wr = t >> 1, wh = t & 1;
        const half8* p = (const half8*)(Wt + wr * 128 + wh * 64);
        _Float16* d = Ws + wr * GP + wh * 64;
#pragma unroll
        for (int j = 0; j < 8; ++j) *(half8*)(d + j * 8) = p[j];
    }
    __syncthreads();

    int wv = t >> 6, l = t & 63;
    int lrow = l & 15;
    int lk8  = (l >> 4) * 8;

    f32x4 acc[8];
#pragma unroll
    for (int n = 0; n < 8; ++n) acc[n] = (f32x4){0.f, 0.f, 0.f, 0.f};

    const _Float16* xbase = Xs + (wv * 16 + lrow) * GP + lk8;
#pragma unroll
    for (int kk = 0; kk < 4; ++kk) {
        half8 a = *(const half8*)(xbase + kk * 32);
#pragma unroll
        for (int n = 0; n < 8; ++n) {
            half8 bf = *(const half8*)(Ws + (n * 16 + lrow) * GP + kk * 32 + lk8);
            acc[n] = __builtin_amdgcn_mfma_f32_16x16x32_f16(a, bf, acc[n], 0, 0, 0);
        }
    }

    // epilogue: h16 stores + fused alpha dot products
    int c = lrow;
    int g = l >> 4;
#pragma unroll
    for (int n = 0; n < 8; ++n) {
#pragma unroll
        for (int r = 0; r < 4; ++r) {
            int row = brow + wv * 16 + g * 4 + r;
            if (row < nrows)
                Hh[(size_t)row * 128 + n * 16 + c] = (_Float16)acc[n][r];
        }
    }
#pragma unroll
    for (int hd = 0; hd < 4; ++hd) {
        float as0 = avs[hd * 32 + c], as1 = avs[hd * 32 + 16 + c];
        float ad0 = avd[hd * 32 + c], ad1 = avd[hd * 32 + 16 + c];
#pragma unroll
        for (int r = 0; r < 4; ++r) {
            float ps = acc[2 * hd][r] * as0 + acc[2 * hd + 1][r] * as1;
            float pd = acc[2 * hd][r] * ad0 + acc[2 * hd + 1][r] * ad1;
            ps += __shfl_xor(ps, 1); ps += __shfl_xor(ps, 2);
            ps += __shfl_xor(ps, 4); ps += __shfl_xor(ps, 8);
            pd += __shfl_xor(pd, 1); pd += __shfl_xor(pd, 2);
            pd += __shfl_xor(pd, 4); pd += __shfl_xor(pd, 8);
            if (c == 0) {
                int row = brow + wv * 16 + g * 4 + r;
                if (row < nrows) {
                    alpha_s[row * 4 + hd] = ps;
                    alpha_d[row * 4 + hd] = pd;
                }
            }
        }
    }
}

// ------- fused attention + gather: 4 edge parities x 16 feature lanes ------
// (round-13 structure: best measured). One wave per node; p = lane>>4 strides
// edges by 4; lane owns 8 features (ft = lane&15): 16 lanes x 16B = full 256B
// fp16 h row per edge. csr_src is ushort (src < 65536). No max-shift (logits
// O(+-6), exp fp32-safe, softmax shift-invariant). Parity partials combined
// via shfl_xor(16)+shfl_xor(32).
template <bool F16OUT>
__global__ __launch_bounds__(256) void att_gather_kernel(
    const unsigned short* __restrict__ csr_src, const int2* __restrict__ node_info,
    const float* __restrict__ alpha_s, const float* __restrict__ alpha_d,
    const _Float16* __restrict__ hbuf, const float* __restrict__ b,
    float* __restrict__ out32, _Float16* __restrict__ out16)
{
    int node = blockIdx.x * 4 + (threadIdx.x >> 6);
    if (node >= NNODES) return;
    int lane = threadIdx.x & 63;
    int p  = lane >> 4;                 // edge parity 0..3
    int ft = lane & 15;                 // feature block
    int f  = ft * 8;                    // features f..f+7
    int hh = ft >> 2;                   // head
    int2 bi = node_info[node];
    int beg = bi.x, end = bi.x + bi.y;
    float ad = alpha_d[node * 4 + hh];

    float acc[8] = {0.f, 0.f, 0.f, 0.f, 0.f, 0.f, 0.f, 0.f};
    float den = 0.f;
    int i = beg + p;
    for (; i + 4 < end; i += 8) {       // 2 independent edges per lane/iter
        int s0 = csr_src[i];
        int s1 = csr_src[i + 4];
        float l0 = alpha_s[s0 * 4 + hh] + ad;
        float l1 = alpha_s[s1 * 4 + hh] + ad;
        half8 h0 = *(const half8*)(hbuf + (size_t)s0 * 128 + f);
        half8 h1 = *(const half8*)(hbuf + (size_t)s1 * 128 + f);
        l0 = fmaxf(l0, 0.2f * l0);      // leaky relu
        l1 = fmaxf(l1, 0.2f * l1);
        float e0 = __expf(l0);
        float e1 = __expf(l1);
        den += e0 + e1;
#pragma unroll
        for (int j = 0; j < 8; ++j) acc[j] = fmaf(e0, (float)h0[j], acc[j]);
#pragma unroll
        for (int j = 0; j < 8; ++j) acc[j] = fmaf(e1, (float)h1[j], acc[j]);
    }
    for (; i < end; i += 4) {           // tail: 0 or 1 edge of this parity
        int s0 = csr_src[i];
        float l0 = alpha_s[s0 * 4 + hh] + ad;
        half8 h0 = *(const half8*)(hbuf + (size_t)s0 * 128 + f);
        l0 = fmaxf(l0, 0.2f * l0);
        float e0 = __expf(l0);
        den += e0;
#pragma unroll
        for (int j = 0; j < 8; ++j) acc[j] = fmaf(e0, (float)h0[j], acc[j]);
    }

    // combine the 4 parities (lane bits 4,5)
#pragma unroll
    for (int j = 0; j < 8; ++j) {
        acc[j] += __shfl_xor(acc[j], 16);
        acc[j] += __shfl_xor(acc[j], 32);
    }
    den += __shfl_xor(den, 16);
    den += __shfl_xor(den, 32);

    if (p == 0) {
        float rd = 1.f / fmaxf(den, 1e-16f);
        float4 bv0 = *(const float4*)(b + f);
        float4 bv1 = *(const float4*)(b + f + 4);
        float x[8];
        x[0] = acc[0] * rd + bv0.x; x[1] = acc[1] * rd + bv0.y;
        x[2] = acc[2] * rd + bv0.z; x[3] = acc[3] * rd + bv0.w;
        x[4] = acc[4] * rd + bv1.x; x[5] = acc[5] * rd + bv1.y;
        x[6] = acc[6] * rd + bv1.z; x[7] = acc[7] * rd + bv1.w;
#pragma unroll
        for (int j = 0; j < 8; ++j) x[j] = (x[j] > 0.f) ? x[j] : expm1f(x[j]);
        if (F16OUT) {
            half8 hv;
#pragma unroll
            for (int j = 0; j < 8; ++j) hv[j] = (_Float16)x[j];
            *(half8*)(out16 + (size_t)node * 128 + f) = hv;
        } else {
            *(float4*)(out32 + (size_t)node * 128 + f) =
                make_float4(x[0], x[1], x[2], x[3]);
            *(float4*)(out32 + (size_t)node * 128 + f + 4) =
                make_float4(x[4], x[5], x[6], x[7]);
        }
    }
}

extern "C" void kernel_launch(void* const* d_in, const int* in_sizes, int n_in,
                              void* d_out, int out_size, void* d_ws, size_t ws_size,
                              hipStream_t stream) {
    const float* X    = (const float*)d_in[0];
    const int*   ei   = (const int*)d_in[1];
    const float* W0   = (const float*)d_in[2];
    const float* as0  = (const float*)d_in[3];
    const float* ad0  = (const float*)d_in[4];
    const float* b0   = (const float*)d_in[5];
    const float* W1   = (const float*)d_in[6];
    const float* as1  = (const float*)d_in[7];
    const float* ad1  = (const float*)d_in[8];
    const float* b1   = (const float*)d_in[9];

    const int* srcp = ei;            // edge_index[0]
    const int* dstp = ei + NEDGES;   // edge_index[1]

    _Float16* h16  = (_Float16*)d_ws;            // 6.4M halves
    _Float16* ho16 = h16 + 6400000;              // 6.4M halves (layer-1 out)
    _Float16* W0t  = ho16 + 6400000;             // 16384
    _Float16* W1t  = W0t + 16384;                // 16384
    float* as_ = (float*)(W1t + 16384);          // 200,000
    float* ad_ = as_ + 200000;                   // 200,000
    unsigned* binned = (unsigned*)(ad_ + 200000);            // (KB+1)*CAPB
    unsigned short* csr_src = (unsigned short*)(binned + (KB + 1) * CAPB);
    int2* node_info = (int2*)(csr_src + ((KB * CAPB + 1) & ~1));  // 50,000
    int*  bincur    = (int*)(node_info + NNODES);                 // KB

    // ---- setup (bincur init + W transposes) + CSR build, layer-invariant --
    setup_kernel<<<64, 256, 0, stream>>>(W0, W1, W0t, W1t, bincur);
    binA_kernel<<<NABLK, 256, 0, stream>>>(srcp, dstp, bincur, binned);
    binB_kernel<<<KB, 256, 0, stream>>>(binned, bincur, csr_src, node_info);

    const int NODE_BLOCKS = (NNODES + 3) / 4;
    const int GEMM_BLOCKS = (NNODES + 63) / 64;

    // layer 0 (fp32 input, converted in staging)
    gemm_mfma_kernel<true><<<GEMM_BLOCKS, 256, 0, stream>>>(
        X, W0t, as0, ad0, h16, as_, ad_, NNODES);
    att_gather_kernel<true><<<NODE_BLOCKS, 256, 0, stream>>>(
        csr_src, node_info, as_, ad_, h16, b0, nullptr, ho16);

    // layer 1 (fp16 input from layer-0 output)
    gemm_mfma_kernel<false><<<GEMM_BLOCKS, 256, 0, stream>>>(
        ho16, W1t, as1, ad1, h16, as_, ad_, NNODES);
    att_gather_kernel<false><<<NODE_BLOCKS, 256, 0, stream>>>(
        csr_src, node_info, as_, ad_, h16, b1, (float*)d_out, nullptr);
}